// Round 7
// baseline (464.992 us; speedup 1.0000x reference)
//
#include <hip/hip_runtime.h>
#include <hip/hip_bf16.h>

typedef short s16x8 __attribute__((ext_vector_type(8)));
typedef float f32x4 __attribute__((ext_vector_type(4)));

#define MFMA_BF16(A, B, C) __builtin_amdgcn_mfma_f32_16x16x32_bf16(A, B, C, 0, 0, 0)

constexpr int Bn = 4, Tn = 2048, Cn = 1024, Hn = 16, Dn = 64;
constexpr int Mn = Bn * Tn;      // 8192
constexpr int Nqkv = 3 * Cn;     // 3072
constexpr float SC = 0.125f * 1.44269504089f;  // 1/sqrt(D) * log2(e)

__device__ __forceinline__ ushort f2bfu(float f) {
    __hip_bfloat16 h = __float2bfloat16(f);
    return *reinterpret_cast<ushort*>(&h);
}
__device__ __forceinline__ uint pkbf(float a, float b) {
    __hip_bfloat162 h = __float22bfloat162_rn(make_float2(a, b));
    return *reinterpret_cast<uint*>(&h);
}

// async global->LDS, 16B per lane; LDS dest = wave-uniform base + lane*16.
__device__ __forceinline__ void gl_lds16(const void* g, void* l) {
    __builtin_amdgcn_global_load_lds(
        (const __attribute__((address_space(1))) void*)(uintptr_t)g,
        (__attribute__((address_space(3))) void*)(uint32_t)(uintptr_t)l,
        16, 0, 0);
}

// ---------------------------------------------------------------------------
// fp32 -> bf16 elementwise (x)
// ---------------------------------------------------------------------------
__global__ __launch_bounds__(256) void conv_bf16_kernel(
    const float* __restrict__ src, ushort* __restrict__ dst, int n4)
{
    int i = blockIdx.x * blockDim.x + threadIdx.x;
    int stride = gridDim.x * blockDim.x;
    for (; i < n4; i += stride) {
        float4 v = ((const float4*)src)[i];
        ushort4 o;
        o.x = f2bfu(v.x); o.y = f2bfu(v.y); o.z = f2bfu(v.z); o.w = f2bfu(v.w);
        ((ushort4*)dst)[i] = o;
    }
}

// ---------------------------------------------------------------------------
// W [K][N] fp32  ->  Wt [N][K] bf16   (64x64 tiles via LDS)
// ---------------------------------------------------------------------------
__global__ __launch_bounds__(256) void transpose_cvt_kernel(
    const float* __restrict__ W, ushort* __restrict__ Wt, int K, int N)
{
    __shared__ __align__(16) float Ls[64][68];
    const int t = threadIdx.x;
    const int n0 = blockIdx.x * 64, k0 = blockIdx.y * 64;
#pragma unroll
    for (int p = 0; p < 4; ++p) {
        int r = (t >> 4) + p * 16;
        int c = (t & 15) * 4;
        *(float4*)&Ls[r][c] = *(const float4*)&W[(size_t)(k0 + r) * N + n0 + c];
    }
    __syncthreads();
    const int n = t >> 2;
    const int ks = (t & 3) * 16;
    union { ushort s[16]; uint4 u[2]; } tmp;
#pragma unroll
    for (int j = 0; j < 16; ++j) tmp.s[j] = f2bfu(Ls[ks + j][n]);
    uint4* dp = (uint4*)&Wt[(size_t)(n0 + n) * K + k0 + ks];
    dp[0] = tmp.u[0];
    dp[1] = tmp.u[1];
}

// ---------------------------------------------------------------------------
// V [bh][t][d] bf16 -> Vt [bh][d][t] bf16 (4x4 in-register transpose)
// ---------------------------------------------------------------------------
__global__ __launch_bounds__(256) void vt_transpose_kernel(
    const ushort* __restrict__ V, ushort* __restrict__ Vt)
{
    const int tid = threadIdx.x;
    const int bh = blockIdx.x;
    const int kt0 = blockIdx.y * 64;
    const ushort* src = V + (size_t)bh * Tn * Dn;
    ushort* dst = Vt + (size_t)bh * Dn * Tn;
    const int vk = (tid & 15) * 4, vd = (tid >> 4) * 4;
    const ushort* g = src + (size_t)(kt0 + vk) * Dn + vd;
    ushort4 v0 = *(const ushort4*)(g);
    ushort4 v1 = *(const ushort4*)(g + Dn);
    ushort4 v2 = *(const ushort4*)(g + 2 * Dn);
    ushort4 v3 = *(const ushort4*)(g + 3 * Dn);
    ushort4 t0, t1, t2, t3;
    t0.x = v0.x; t0.y = v1.x; t0.z = v2.x; t0.w = v3.x;
    t1.x = v0.y; t1.y = v1.y; t1.z = v2.y; t1.w = v3.y;
    t2.x = v0.z; t2.y = v1.z; t2.z = v2.z; t2.w = v3.z;
    t3.x = v0.w; t3.y = v1.w; t3.z = v2.w; t3.w = v3.w;
    *(ushort4*)(dst + (size_t)(vd + 0) * Tn + kt0 + vk) = t0;
    *(ushort4*)(dst + (size_t)(vd + 1) * Tn + kt0 + vk) = t1;
    *(ushort4*)(dst + (size_t)(vd + 2) * Tn + kt0 + vk) = t2;
    *(ushort4*)(dst + (size_t)(vd + 3) * Tn + kt0 + vk) = t3;
}

// ---------------------------------------------------------------------------
// QKV GEMM, m97-style staging. Q outputs pre-scaled by SC (exp2 domain).
// ---------------------------------------------------------------------------
__global__ __launch_bounds__(256) void qkv_gemm_mfma(
    const ushort* __restrict__ A, const ushort* __restrict__ Bt,
    const float* __restrict__ bias,
    ushort* __restrict__ Qo, ushort* __restrict__ Ko, ushort* __restrict__ Vo)
{
    __shared__ __align__(16) ushort As[128 * 64];
    __shared__ __align__(16) ushort Bs[128 * 64];
    const int tid = threadIdx.x;
    const int m0 = blockIdx.x * 128, n0 = blockIdx.y * 128;
    const int w = tid >> 6, lane = tid & 63, l15 = lane & 15, qd = lane >> 4;
    const int wm = (w >> 1) * 64, wn = (w & 1) * 64;
    const int lrow = lane >> 3;
    const int lchunk = (lane & 7) ^ (lrow & 7);

    const ushort* gA = A + (size_t)(m0 + w * 32 + lrow) * Cn + lchunk * 8;
    const ushort* gB = Bt + (size_t)(n0 + w * 32 + lrow) * Cn + lchunk * 8;
    ushort* lA = &As[(w * 32) * 64];
    ushort* lB = &Bs[(w * 32) * 64];

    f32x4 acc[4][4] = {};

    for (int k0 = 0; k0 < Cn; k0 += 64) {
        __syncthreads();
#pragma unroll
        for (int t = 0; t < 4; ++t) {
            gl_lds16(gA + (size_t)t * 8 * Cn + k0, lA + t * 8 * 64);
            gl_lds16(gB + (size_t)t * 8 * Cn + k0, lB + t * 8 * 64);
        }
        __syncthreads();
#pragma unroll
        for (int ks = 0; ks < 2; ++ks) {
            const int xs = (((ks * 4 + qd) ^ (l15 & 7))) * 8;
            s16x8 af[4], bfr[4];
#pragma unroll
            for (int i = 0; i < 4; ++i) {
                af[i]  = *(const s16x8*)&As[(wm + i * 16 + l15) * 64 + xs];
                bfr[i] = *(const s16x8*)&Bs[(wn + i * 16 + l15) * 64 + xs];
            }
#pragma unroll
            for (int mt = 0; mt < 4; ++mt)
#pragma unroll
                for (int nt = 0; nt < 4; ++nt)
                    acc[mt][nt] = MFMA_BF16(af[mt], bfr[nt], acc[mt][nt]);
        }
    }

#pragma unroll
    for (int nt = 0; nt < 4; ++nt) {
        int n_g = n0 + wn + nt * 16 + l15;
        float bv = bias[n_g];
        int sel = n_g >> 10;
        int h = (n_g >> 6) & 15;
        int d = n_g & 63;
        ushort* O = (sel == 0) ? Qo : ((sel == 1) ? Ko : Vo);
        float scl = (sel == 0) ? SC : 1.0f;
#pragma unroll
        for (int mt = 0; mt < 4; ++mt) {
#pragma unroll
            for (int r = 0; r < 4; ++r) {
                int m_g = m0 + wm + mt * 16 + qd * 4 + r;
                int b = m_g >> 11, t = m_g & 2047;
                O[(((size_t)(b * Hn + h) * Tn + t) << 6) + d] =
                    f2bfu((acc[mt][nt][r] + bv) * scl);
            }
        }
    }
}

// ---------------------------------------------------------------------------
// Barrier-free MFMA flash attention. All MFMA fragments (Q, K, V^T) are
// contiguous 16B GLOBAL loads (V pre-transposed to [bh][d][t]); no cross-
// wave LDS staging, no __syncthreads anywhere. Waves run independently;
// K frags for kt+1 prefetch into registers during kt's softmax. Only the
// wave-private P^T C->A layout round-trip uses LDS (8 KB/block).
// Grid (bh=64, pair=16): XCD-local K/V/Vt reuse (linear%8 == bh%8).
// ---------------------------------------------------------------------------
__global__ __launch_bounds__(256, 3) void attn_mfma(
    const ushort* __restrict__ Q, const ushort* __restrict__ K,
    const ushort* __restrict__ Vt, ushort* __restrict__ Y)
{
    __shared__ __align__(16) ushort Ps[64 * 64];   // 4 waves x 16 rows x 64 keys

    const int tid = threadIdx.x;
    const int bh = blockIdx.x, bx = blockIdx.y;
    const int w = tid >> 6, lane = tid & 63, l15 = lane & 15, qd = lane >> 4;
    const size_t base = (size_t)bh * Tn * Dn;
    const int q_l = w * 16 + l15;
    const int frow = (w * 16 + l15) * 64;
    const int fx0 = ((0 * 4 + qd) ^ (l15 & 7)) * 8;
    const int fx1 = ((1 * 4 + qd) ^ (l15 & 7)) * 8;
    const int b = bh >> 4, h = bh & 15;

    // lane-resolved fragment base pointers
    const ushort* Kf = K + base + (size_t)l15 * Dn + qd * 8;        // + key*64
    const ushort* Vf = Vt + base + (size_t)l15 * Tn + qd * 8;       // + d16*Tn + key
    const ushort* Qp = Q + base + (size_t)l15 * Dn + qd * 8;        // + qrow*64

#pragma unroll
    for (int half = 0; half < 2; ++half) {
        const int qt = half ? (31 - bx) : bx;

        const ushort* qrow = Qp + (size_t)(qt * 64 + w * 16) * Dn;
        s16x8 qf0 = *(const s16x8*)(qrow);
        s16x8 qf1 = *(const s16x8*)(qrow + 32);

        float m_run = -1e30f, l_run = 0.f;
        f32x4 o[4] = {};   // O^T[d=dt*16+qd*4+r][q=l15]

        s16x8 kfa[8], kfb[8];
#pragma unroll
        for (int ks = 0; ks < 2; ++ks)
#pragma unroll
            for (int nt = 0; nt < 4; ++nt)
                kfa[ks * 4 + nt] = *(const s16x8*)(Kf + (size_t)(nt * 16) * Dn + ks * 32);

        auto tile = [&](int kt, s16x8* kf, s16x8* kfn, bool pref) {
            // V fragments for this kt (independent; overlap S+softmax)
            s16x8 vf[8];
#pragma unroll
            for (int ks = 0; ks < 2; ++ks)
#pragma unroll
                for (int dt = 0; dt < 4; ++dt)
                    vf[ks * 4 + dt] = *(const s16x8*)(
                        Vf + (size_t)(dt * 16) * Tn + kt * 64 + ks * 32);

            // S^T = K·Q^T (exp2 domain via pre-scaled Q)
            f32x4 s[4] = {};
#pragma unroll
            for (int nt = 0; nt < 4; ++nt)
                s[nt] = MFMA_BF16(kf[nt], qf0, s[nt]);
#pragma unroll
            for (int nt = 0; nt < 4; ++nt)
                s[nt] = MFMA_BF16(kf[4 + nt], qf1, s[nt]);

            if (pref) {   // prefetch K tile kt+1 during softmax
                const ushort* kn = Kf + (size_t)(kt + 1) * 64 * Dn;
#pragma unroll
                for (int ks = 0; ks < 2; ++ks)
#pragma unroll
                    for (int nt = 0; nt < 4; ++nt)
                        kfn[ks * 4 + nt] = *(const s16x8*)(
                            kn + (size_t)(nt * 16) * Dn + ks * 32);
            }

            if (kt == qt) {
#pragma unroll
                for (int nt = 0; nt < 4; ++nt)
#pragma unroll
                    for (int r = 0; r < 4; ++r)
                        if (nt * 16 + qd * 4 + r > q_l) s[nt][r] = -1e30f;
            }

            // online softmax over keys: 15 in-lane fmax + 2 shuffles
            float mx = s[0][0];
#pragma unroll
            for (int nt = 0; nt < 4; ++nt)
#pragma unroll
                for (int r = 0; r < 4; ++r) mx = fmaxf(mx, s[nt][r]);
            mx = fmaxf(mx, __shfl_xor(mx, 16));
            mx = fmaxf(mx, __shfl_xor(mx, 32));

            if (__any(mx > m_run)) {
                float m_new = fmaxf(m_run, mx);
                float alpha = exp2f(m_run - m_new);
                m_run = m_new;
                l_run *= alpha;
#pragma unroll
                for (int dt = 0; dt < 4; ++dt)
#pragma unroll
                    for (int r = 0; r < 4; ++r) o[dt][r] *= alpha;
            }
            float ls = 0.f;
#pragma unroll
            for (int nt = 0; nt < 4; ++nt)
#pragma unroll
                for (int r = 0; r < 4; ++r) {
                    float p = exp2f(s[nt][r] - m_run);
                    s[nt][r] = p;
                    ls += p;
                }
            ls += __shfl_xor(ls, 16);
            ls += __shfl_xor(ls, 32);
            l_run += ls;

            // P^T -> wave-private LDS rows (packed bf16 pairs)
#pragma unroll
            for (int nt = 0; nt < 4; ++nt) {
                uint2 pk;
                pk.x = pkbf(s[nt][0], s[nt][1]);
                pk.y = pkbf(s[nt][2], s[nt][3]);
                const int pc = 2 * nt + (qd >> 1), po = (qd & 1) * 4;
                *(uint2*)&Ps[frow + ((pc ^ (l15 & 7)) * 8) + po] = pk;
            }

            // O^T += V^T · P^T  (same-wave LDS round trip; no barrier)
            {
                s16x8 pb = *(const s16x8*)&Ps[frow + fx0];
#pragma unroll
                for (int dt = 0; dt < 4; ++dt)
                    o[dt] = MFMA_BF16(vf[dt], pb, o[dt]);
                pb = *(const s16x8*)&Ps[frow + fx1];
#pragma unroll
                for (int dt = 0; dt < 4; ++dt)
                    o[dt] = MFMA_BF16(vf[4 + dt], pb, o[dt]);
            }
        };

        for (int kt = 0; kt <= qt; kt += 2) {
            tile(kt, kfa, kfb, kt < qt);
            if (kt + 1 > qt) break;
            tile(kt + 1, kfb, kfa, kt + 1 < qt);
        }

        // epilogue: O^T[d][q=l15] -> Y[b, t=q_global, h*64+d]
        const float inv = 1.f / l_run;
        const int t_g = qt * 64 + w * 16 + l15;
        ushort* yp = Y + ((size_t)(b * Tn + t_g)) * Cn + h * Dn + qd * 4;
#pragma unroll
        for (int dt = 0; dt < 4; ++dt) {
            uint2 pk;
            pk.x = pkbf(o[dt][0] * inv, o[dt][1] * inv);
            pk.y = pkbf(o[dt][2] * inv, o[dt][3] * inv);
            *(uint2*)(yp + dt * 16) = pk;
        }
    }
}

// ---------------------------------------------------------------------------
// Proj GEMM: Y [8192][1024] bf16, Wt [1024][1024] bf16 -> out fp32
// ---------------------------------------------------------------------------
__global__ __launch_bounds__(256) void proj_gemm_mfma(
    const ushort* __restrict__ A, const ushort* __restrict__ Bt,
    const float* __restrict__ bias, float* __restrict__ out)
{
    __shared__ __align__(16) ushort As[128 * 64];
    __shared__ __align__(16) ushort Bs[128 * 64];
    const int tid = threadIdx.x;
    const int m0 = blockIdx.x * 128, n0 = blockIdx.y * 128;
    const int w = tid >> 6, lane = tid & 63, l15 = lane & 15, qd = lane >> 4;
    const int wm = (w >> 1) * 64, wn = (w & 1) * 64;
    const int lrow = lane >> 3;
    const int lchunk = (lane & 7) ^ (lrow & 7);

    const ushort* gA = A + (size_t)(m0 + w * 32 + lrow) * Cn + lchunk * 8;
    const ushort* gB = Bt + (size_t)(n0 + w * 32 + lrow) * Cn + lchunk * 8;
    ushort* lA = &As[(w * 32) * 64];
    ushort* lB = &Bs[(w * 32) * 64];

    f32x4 acc[4][4] = {};

    for (int k0 = 0; k0 < Cn; k0 += 64) {
        __syncthreads();
#pragma unroll
        for (int t = 0; t < 4; ++t) {
            gl_lds16(gA + (size_t)t * 8 * Cn + k0, lA + t * 8 * 64);
            gl_lds16(gB + (size_t)t * 8 * Cn + k0, lB + t * 8 * 64);
        }
        __syncthreads();
#pragma unroll
        for (int ks = 0; ks < 2; ++ks) {
            const int xs = (((ks * 4 + qd) ^ (l15 & 7))) * 8;
            s16x8 af[4], bfr[4];
#pragma unroll
            for (int i = 0; i < 4; ++i) {
                af[i]  = *(const s16x8*)&As[(wm + i * 16 + l15) * 64 + xs];
                bfr[i] = *(const s16x8*)&Bs[(wn + i * 16 + l15) * 64 + xs];
            }
#pragma unroll
            for (int mt = 0; mt < 4; ++mt)
#pragma unroll
                for (int nt = 0; nt < 4; ++nt)
                    acc[mt][nt] = MFMA_BF16(af[mt], bfr[nt], acc[mt][nt]);
        }
    }

#pragma unroll
    for (int nt = 0; nt < 4; ++nt) {
        int n_g = n0 + wn + nt * 16 + l15;
        float bv = bias[n_g];
#pragma unroll
        for (int mt = 0; mt < 4; ++mt) {
#pragma unroll
            for (int r = 0; r < 4; ++r) {
                int m_g = m0 + wm + mt * 16 + qd * 4 + r;
                out[(size_t)m_g * Cn + n_g] = acc[mt][nt][r] + bv;
            }
        }
    }
}

// ---------------------------------------------------------------------------
extern "C" void kernel_launch(void* const* d_in, const int* in_sizes, int n_in,
                              void* d_out, int out_size, void* d_ws, size_t ws_size,
                              hipStream_t stream) {
    const float* x      = (const float*)d_in[0];
    const float* W_attn = (const float*)d_in[1];
    const float* b_attn = (const float*)d_in[2];
    const float* W_proj = (const float*)d_in[3];
    const float* b_proj = (const float*)d_in[4];
    float* out = (float*)d_out;

    // ws: Q, K, V [B,H,T,D] bf16, Y [B,T,C] bf16
    constexpr size_t PER = (size_t)Mn * Cn;  // 8388608 elems
    ushort* Qb = (ushort*)d_ws;
    ushort* Kb = Qb + PER;
    ushort* Vb = Kb + PER;
    ushort* Yb = Vb + PER;

    // d_out as scratch (33.5 MB):
    //   phase 1 (pre-GEMM): WtA [3072][1024] bf16 (6.3MB) + x_bf (16.8MB)
    //   phase 2 (post-GEMM, pre-proj): Vtb [bh][d][t] bf16 (16.8MB) at offset 0
    ushort* WtA  = (ushort*)d_out;
    ushort* x_bf = WtA + (size_t)Nqkv * Cn;
    ushort* Vtb  = (ushort*)d_out;     // overwrites WtA/x_bf after qkv_gemm
    ushort* WtP  = Qb;                 // reuses Q buffer (dead after attention)

    conv_bf16_kernel<<<1024, 256, 0, stream>>>(x, x_bf, (int)(PER / 4));
    transpose_cvt_kernel<<<dim3(Nqkv / 64, Cn / 64), 256, 0, stream>>>(
        W_attn, WtA, Cn, Nqkv);
    qkv_gemm_mfma<<<dim3(Mn / 128, Nqkv / 128), 256, 0, stream>>>(
        x_bf, WtA, b_attn, Qb, Kb, Vb);
    vt_transpose_kernel<<<dim3(Bn * Hn, Tn / 64), 256, 0, stream>>>(Vb, Vtb);
    attn_mfma<<<dim3(Bn * Hn, 16), 256, 0, stream>>>(Qb, Kb, Vtb, Yb);
    transpose_cvt_kernel<<<dim3(Cn / 64, Cn / 64), 256, 0, stream>>>(
        W_proj, WtP, Cn, Cn);
    proj_gemm_mfma<<<dim3(Mn / 128, Cn / 128), 256, 0, stream>>>(
        Yb, WtP, b_proj, out);
}

// Round 8
// 421.721 us; speedup vs baseline: 1.1026x; 1.1026x over previous
//
#include <hip/hip_runtime.h>
#include <hip/hip_bf16.h>

typedef short s16x8 __attribute__((ext_vector_type(8)));
typedef float f32x4 __attribute__((ext_vector_type(4)));

#define MFMA_BF16(A, B, C) __builtin_amdgcn_mfma_f32_16x16x32_bf16(A, B, C, 0, 0, 0)

constexpr int Bn = 4, Tn = 2048, Cn = 1024, Hn = 16, Dn = 64;
constexpr int Mn = Bn * Tn;      // 8192
constexpr int Nqkv = 3 * Cn;     // 3072
constexpr float SC = 0.125f * 1.44269504089f;  // 1/sqrt(D) * log2(e)

__device__ __forceinline__ ushort f2bfu(float f) {
    __hip_bfloat16 h = __float2bfloat16(f);
    return *reinterpret_cast<ushort*>(&h);
}
__device__ __forceinline__ uint pkbf(float a, float b) {
    __hip_bfloat162 h = __float22bfloat162_rn(make_float2(a, b));
    return *reinterpret_cast<uint*>(&h);
}

// async global->LDS, 16B per lane; LDS dest = wave-uniform base + lane*16.
__device__ __forceinline__ void gl_lds16(const void* g, void* l) {
    __builtin_amdgcn_global_load_lds(
        (const __attribute__((address_space(1))) void*)(uintptr_t)g,
        (__attribute__((address_space(3))) void*)(uint32_t)(uintptr_t)l,
        16, 0, 0);
}

// ---------------------------------------------------------------------------
// fp32 -> bf16 elementwise (x)
// ---------------------------------------------------------------------------
__global__ __launch_bounds__(256) void conv_bf16_kernel(
    const float* __restrict__ src, ushort* __restrict__ dst, int n4)
{
    int i = blockIdx.x * blockDim.x + threadIdx.x;
    int stride = gridDim.x * blockDim.x;
    for (; i < n4; i += stride) {
        float4 v = ((const float4*)src)[i];
        ushort4 o;
        o.x = f2bfu(v.x); o.y = f2bfu(v.y); o.z = f2bfu(v.z); o.w = f2bfu(v.w);
        ((ushort4*)dst)[i] = o;
    }
}

// ---------------------------------------------------------------------------
// W [K][N] fp32  ->  Wt [N][K] bf16   (64x64 tiles via LDS)
// ---------------------------------------------------------------------------
__global__ __launch_bounds__(256) void transpose_cvt_kernel(
    const float* __restrict__ W, ushort* __restrict__ Wt, int K, int N)
{
    __shared__ __align__(16) float Ls[64][68];
    const int t = threadIdx.x;
    const int n0 = blockIdx.x * 64, k0 = blockIdx.y * 64;
#pragma unroll
    for (int p = 0; p < 4; ++p) {
        int r = (t >> 4) + p * 16;
        int c = (t & 15) * 4;
        *(float4*)&Ls[r][c] = *(const float4*)&W[(size_t)(k0 + r) * N + n0 + c];
    }
    __syncthreads();
    const int n = t >> 2;
    const int ks = (t & 3) * 16;
    union { ushort s[16]; uint4 u[2]; } tmp;
#pragma unroll
    for (int j = 0; j < 16; ++j) tmp.s[j] = f2bfu(Ls[ks + j][n]);
    uint4* dp = (uint4*)&Wt[(size_t)(n0 + n) * K + k0 + ks];
    dp[0] = tmp.u[0];
    dp[1] = tmp.u[1];
}

// ---------------------------------------------------------------------------
// V [bh][t][d] bf16 -> Vt [bh][d][t] bf16 (4x4 in-register transpose)
// ---------------------------------------------------------------------------
__global__ __launch_bounds__(256) void vt_transpose_kernel(
    const ushort* __restrict__ V, ushort* __restrict__ Vt)
{
    const int tid = threadIdx.x;
    const int bh = blockIdx.x;
    const int kt0 = blockIdx.y * 64;
    const ushort* src = V + (size_t)bh * Tn * Dn;
    ushort* dst = Vt + (size_t)bh * Dn * Tn;
    const int vk = (tid & 15) * 4, vd = (tid >> 4) * 4;
    const ushort* g = src + (size_t)(kt0 + vk) * Dn + vd;
    ushort4 v0 = *(const ushort4*)(g);
    ushort4 v1 = *(const ushort4*)(g + Dn);
    ushort4 v2 = *(const ushort4*)(g + 2 * Dn);
    ushort4 v3 = *(const ushort4*)(g + 3 * Dn);
    ushort4 t0, t1, t2, t3;
    t0.x = v0.x; t0.y = v1.x; t0.z = v2.x; t0.w = v3.x;
    t1.x = v0.y; t1.y = v1.y; t1.z = v2.y; t1.w = v3.y;
    t2.x = v0.z; t2.y = v1.z; t2.z = v2.z; t2.w = v3.z;
    t3.x = v0.w; t3.y = v1.w; t3.z = v2.w; t3.w = v3.w;
    *(ushort4*)(dst + (size_t)(vd + 0) * Tn + kt0 + vk) = t0;
    *(ushort4*)(dst + (size_t)(vd + 1) * Tn + kt0 + vk) = t1;
    *(ushort4*)(dst + (size_t)(vd + 2) * Tn + kt0 + vk) = t2;
    *(ushort4*)(dst + (size_t)(vd + 3) * Tn + kt0 + vk) = t3;
}

// ---------------------------------------------------------------------------
// QKV GEMM, m97-style staging. Q outputs pre-scaled by SC (exp2 domain).
// ---------------------------------------------------------------------------
__global__ __launch_bounds__(256) void qkv_gemm_mfma(
    const ushort* __restrict__ A, const ushort* __restrict__ Bt,
    const float* __restrict__ bias,
    ushort* __restrict__ Qo, ushort* __restrict__ Ko, ushort* __restrict__ Vo)
{
    __shared__ __align__(16) ushort As[128 * 64];
    __shared__ __align__(16) ushort Bs[128 * 64];
    const int tid = threadIdx.x;
    const int m0 = blockIdx.x * 128, n0 = blockIdx.y * 128;
    const int w = tid >> 6, lane = tid & 63, l15 = lane & 15, qd = lane >> 4;
    const int wm = (w >> 1) * 64, wn = (w & 1) * 64;
    const int lrow = lane >> 3;
    const int lchunk = (lane & 7) ^ (lrow & 7);

    const ushort* gA = A + (size_t)(m0 + w * 32 + lrow) * Cn + lchunk * 8;
    const ushort* gB = Bt + (size_t)(n0 + w * 32 + lrow) * Cn + lchunk * 8;
    ushort* lA = &As[(w * 32) * 64];
    ushort* lB = &Bs[(w * 32) * 64];

    f32x4 acc[4][4] = {};

    for (int k0 = 0; k0 < Cn; k0 += 64) {
        __syncthreads();
#pragma unroll
        for (int t = 0; t < 4; ++t) {
            gl_lds16(gA + (size_t)t * 8 * Cn + k0, lA + t * 8 * 64);
            gl_lds16(gB + (size_t)t * 8 * Cn + k0, lB + t * 8 * 64);
        }
        __syncthreads();
#pragma unroll
        for (int ks = 0; ks < 2; ++ks) {
            const int xs = (((ks * 4 + qd) ^ (l15 & 7))) * 8;
            s16x8 af[4], bfr[4];
#pragma unroll
            for (int i = 0; i < 4; ++i) {
                af[i]  = *(const s16x8*)&As[(wm + i * 16 + l15) * 64 + xs];
                bfr[i] = *(const s16x8*)&Bs[(wn + i * 16 + l15) * 64 + xs];
            }
#pragma unroll
            for (int mt = 0; mt < 4; ++mt)
#pragma unroll
                for (int nt = 0; nt < 4; ++nt)
                    acc[mt][nt] = MFMA_BF16(af[mt], bfr[nt], acc[mt][nt]);
        }
    }

#pragma unroll
    for (int nt = 0; nt < 4; ++nt) {
        int n_g = n0 + wn + nt * 16 + l15;
        float bv = bias[n_g];
        int sel = n_g >> 10;
        int h = (n_g >> 6) & 15;
        int d = n_g & 63;
        ushort* O = (sel == 0) ? Qo : ((sel == 1) ? Ko : Vo);
        float scl = (sel == 0) ? SC : 1.0f;
#pragma unroll
        for (int mt = 0; mt < 4; ++mt) {
#pragma unroll
            for (int r = 0; r < 4; ++r) {
                int m_g = m0 + wm + mt * 16 + qd * 4 + r;
                int b = m_g >> 11, t = m_g & 2047;
                O[(((size_t)(b * Hn + h) * Tn + t) << 6) + d] =
                    f2bfu((acc[mt][nt][r] + bv) * scl);
            }
        }
    }
}

// ---------------------------------------------------------------------------
// Barrier-free MFMA flash attention. All MFMA fragments (Q, K, V^T) are
// contiguous 16B GLOBAL loads (V pre-transposed to [bh][d][t]); no cross-
// wave LDS staging, no __syncthreads. All fragment arrays are constant-
// indexed locals (never address-taken) -> guaranteed VGPR promotion
// (R7's lambda passed them by pointer -> scratch spill -> 176 MB writes).
// No K double-buffer: loads at tile top, TLP (12 waves/CU) hides latency.
// Grid (bh=64, pair=16): XCD-local K/Vt reuse (linear%8 == bh%8).
// ---------------------------------------------------------------------------
__global__ __launch_bounds__(256, 3) void attn_mfma(
    const ushort* __restrict__ Q, const ushort* __restrict__ K,
    const ushort* __restrict__ Vt, ushort* __restrict__ Y)
{
    __shared__ __align__(16) ushort Ps[64 * 64];   // 4 waves x 16 rows x 64 keys

    const int tid = threadIdx.x;
    const int bh = blockIdx.x, bx = blockIdx.y;
    const int w = tid >> 6, lane = tid & 63, l15 = lane & 15, qd = lane >> 4;
    const size_t base = (size_t)bh * Tn * Dn;
    const int q_l = w * 16 + l15;
    const int frow = (w * 16 + l15) * 64;
    const int fx0 = ((0 * 4 + qd) ^ (l15 & 7)) * 8;
    const int fx1 = ((1 * 4 + qd) ^ (l15 & 7)) * 8;
    const int b = bh >> 4, h = bh & 15;

    // lane-resolved fragment base pointers
    const ushort* Kf = K + base + (size_t)l15 * Dn + qd * 8;    // + key*64
    const ushort* Vf = Vt + base + (size_t)l15 * Tn + qd * 8;   // + d16*Tn + key
    const ushort* Qp = Q + base + (size_t)l15 * Dn + qd * 8;    // + qrow*64

#pragma unroll
    for (int half = 0; half < 2; ++half) {
        const int qt = half ? (31 - bx) : bx;

        const ushort* qrow = Qp + (size_t)(qt * 64 + w * 16) * Dn;
        s16x8 qf0 = *(const s16x8*)(qrow);
        s16x8 qf1 = *(const s16x8*)(qrow + 32);

        float m_run = -1e30f, l_run = 0.f;
        f32x4 o[4] = {};   // O^T[d=dt*16+qd*4+r][q=l15]

        for (int kt = 0; kt <= qt; ++kt) {
            // K fragments for this tile (constant-index array -> VGPRs)
            const ushort* kb = Kf + (size_t)kt * 64 * Dn;
            s16x8 kf[8];
#pragma unroll
            for (int ks = 0; ks < 2; ++ks)
#pragma unroll
                for (int nt = 0; nt < 4; ++nt)
                    kf[ks * 4 + nt] = *(const s16x8*)(
                        kb + (size_t)(nt * 16) * Dn + ks * 32);

            // V fragments (issued early; consumed at PV)
            s16x8 vf[8];
#pragma unroll
            for (int ks = 0; ks < 2; ++ks)
#pragma unroll
                for (int dt = 0; dt < 4; ++dt)
                    vf[ks * 4 + dt] = *(const s16x8*)(
                        Vf + (size_t)(dt * 16) * Tn + kt * 64 + ks * 32);

            // S^T = K·Q^T (exp2 domain via pre-scaled Q)
            f32x4 s[4] = {};
#pragma unroll
            for (int nt = 0; nt < 4; ++nt)
                s[nt] = MFMA_BF16(kf[nt], qf0, s[nt]);
#pragma unroll
            for (int nt = 0; nt < 4; ++nt)
                s[nt] = MFMA_BF16(kf[4 + nt], qf1, s[nt]);

            if (kt == qt) {
#pragma unroll
                for (int nt = 0; nt < 4; ++nt)
#pragma unroll
                    for (int r = 0; r < 4; ++r)
                        if (nt * 16 + qd * 4 + r > q_l) s[nt][r] = -1e30f;
            }

            // online softmax over keys: 15 in-lane fmax + 2 shuffles
            float mx = s[0][0];
#pragma unroll
            for (int nt = 0; nt < 4; ++nt)
#pragma unroll
                for (int r = 0; r < 4; ++r) mx = fmaxf(mx, s[nt][r]);
            mx = fmaxf(mx, __shfl_xor(mx, 16));
            mx = fmaxf(mx, __shfl_xor(mx, 32));

            if (__any(mx > m_run)) {
                float m_new = fmaxf(m_run, mx);
                float alpha = exp2f(m_run - m_new);
                m_run = m_new;
                l_run *= alpha;
#pragma unroll
                for (int dt = 0; dt < 4; ++dt)
#pragma unroll
                    for (int r = 0; r < 4; ++r) o[dt][r] *= alpha;
            }
            float ls = 0.f;
#pragma unroll
            for (int nt = 0; nt < 4; ++nt)
#pragma unroll
                for (int r = 0; r < 4; ++r) {
                    float p = exp2f(s[nt][r] - m_run);
                    s[nt][r] = p;
                    ls += p;
                }
            ls += __shfl_xor(ls, 16);
            ls += __shfl_xor(ls, 32);
            l_run += ls;

            // P^T -> wave-private LDS rows (packed bf16 pairs)
#pragma unroll
            for (int nt = 0; nt < 4; ++nt) {
                uint2 pk;
                pk.x = pkbf(s[nt][0], s[nt][1]);
                pk.y = pkbf(s[nt][2], s[nt][3]);
                const int pc = 2 * nt + (qd >> 1), po = (qd & 1) * 4;
                *(uint2*)&Ps[frow + ((pc ^ (l15 & 7)) * 8) + po] = pk;
            }

            // O^T += V^T · P^T  (same-wave LDS round trip; no barrier)
            {
                s16x8 pb = *(const s16x8*)&Ps[frow + fx0];
#pragma unroll
                for (int dt = 0; dt < 4; ++dt)
                    o[dt] = MFMA_BF16(vf[dt], pb, o[dt]);
                pb = *(const s16x8*)&Ps[frow + fx1];
#pragma unroll
                for (int dt = 0; dt < 4; ++dt)
                    o[dt] = MFMA_BF16(vf[4 + dt], pb, o[dt]);
            }
        }

        // epilogue: O^T[d][q=l15] -> Y[b, t=q_global, h*64+d]
        const float inv = 1.f / l_run;
        const int t_g = qt * 64 + w * 16 + l15;
        ushort* yp = Y + ((size_t)(b * Tn + t_g)) * Cn + h * Dn + qd * 4;
#pragma unroll
        for (int dt = 0; dt < 4; ++dt) {
            uint2 pk;
            pk.x = pkbf(o[dt][0] * inv, o[dt][1] * inv);
            pk.y = pkbf(o[dt][2] * inv, o[dt][3] * inv);
            *(uint2*)(yp + dt * 16) = pk;
        }
    }
}

// ---------------------------------------------------------------------------
// Proj GEMM: Y [8192][1024] bf16, Wt [1024][1024] bf16 -> out fp32
// ---------------------------------------------------------------------------
__global__ __launch_bounds__(256) void proj_gemm_mfma(
    const ushort* __restrict__ A, const ushort* __restrict__ Bt,
    const float* __restrict__ bias, float* __restrict__ out)
{
    __shared__ __align__(16) ushort As[128 * 64];
    __shared__ __align__(16) ushort Bs[128 * 64];
    const int tid = threadIdx.x;
    const int m0 = blockIdx.x * 128, n0 = blockIdx.y * 128;
    const int w = tid >> 6, lane = tid & 63, l15 = lane & 15, qd = lane >> 4;
    const int wm = (w >> 1) * 64, wn = (w & 1) * 64;
    const int lrow = lane >> 3;
    const int lchunk = (lane & 7) ^ (lrow & 7);

    const ushort* gA = A + (size_t)(m0 + w * 32 + lrow) * Cn + lchunk * 8;
    const ushort* gB = Bt + (size_t)(n0 + w * 32 + lrow) * Cn + lchunk * 8;
    ushort* lA = &As[(w * 32) * 64];
    ushort* lB = &Bs[(w * 32) * 64];

    f32x4 acc[4][4] = {};

    for (int k0 = 0; k0 < Cn; k0 += 64) {
        __syncthreads();
#pragma unroll
        for (int t = 0; t < 4; ++t) {
            gl_lds16(gA + (size_t)t * 8 * Cn + k0, lA + t * 8 * 64);
            gl_lds16(gB + (size_t)t * 8 * Cn + k0, lB + t * 8 * 64);
        }
        __syncthreads();
#pragma unroll
        for (int ks = 0; ks < 2; ++ks) {
            const int xs = (((ks * 4 + qd) ^ (l15 & 7))) * 8;
            s16x8 af[4], bfr[4];
#pragma unroll
            for (int i = 0; i < 4; ++i) {
                af[i]  = *(const s16x8*)&As[(wm + i * 16 + l15) * 64 + xs];
                bfr[i] = *(const s16x8*)&Bs[(wn + i * 16 + l15) * 64 + xs];
            }
#pragma unroll
            for (int mt = 0; mt < 4; ++mt)
#pragma unroll
                for (int nt = 0; nt < 4; ++nt)
                    acc[mt][nt] = MFMA_BF16(af[mt], bfr[nt], acc[mt][nt]);
        }
    }

#pragma unroll
    for (int nt = 0; nt < 4; ++nt) {
        int n_g = n0 + wn + nt * 16 + l15;
        float bv = bias[n_g];
#pragma unroll
        for (int mt = 0; mt < 4; ++mt) {
#pragma unroll
            for (int r = 0; r < 4; ++r) {
                int m_g = m0 + wm + mt * 16 + qd * 4 + r;
                out[(size_t)m_g * Cn + n_g] = acc[mt][nt][r] + bv;
            }
        }
    }
}

// ---------------------------------------------------------------------------
extern "C" void kernel_launch(void* const* d_in, const int* in_sizes, int n_in,
                              void* d_out, int out_size, void* d_ws, size_t ws_size,
                              hipStream_t stream) {
    const float* x      = (const float*)d_in[0];
    const float* W_attn = (const float*)d_in[1];
    const float* b_attn = (const float*)d_in[2];
    const float* W_proj = (const float*)d_in[3];
    const float* b_proj = (const float*)d_in[4];
    float* out = (float*)d_out;

    // ws: Q, K, V [B,H,T,D] bf16, Y [B,T,C] bf16
    constexpr size_t PER = (size_t)Mn * Cn;  // 8388608 elems
    ushort* Qb = (ushort*)d_ws;
    ushort* Kb = Qb + PER;
    ushort* Vb = Kb + PER;
    ushort* Yb = Vb + PER;

    // d_out as scratch (33.5 MB):
    //   phase 1 (pre-GEMM): WtA [3072][1024] bf16 (6.3MB) + x_bf (16.8MB)
    //   phase 2 (post-GEMM, pre-proj): Vtb [bh][d][t] bf16 (16.8MB) at offset 0
    ushort* WtA  = (ushort*)d_out;
    ushort* x_bf = WtA + (size_t)Nqkv * Cn;
    ushort* Vtb  = (ushort*)d_out;     // overwrites WtA/x_bf after qkv_gemm
    ushort* WtP  = Qb;                 // reuses Q buffer (dead after attention)

    conv_bf16_kernel<<<1024, 256, 0, stream>>>(x, x_bf, (int)(PER / 4));
    transpose_cvt_kernel<<<dim3(Nqkv / 64, Cn / 64), 256, 0, stream>>>(
        W_attn, WtA, Cn, Nqkv);
    qkv_gemm_mfma<<<dim3(Mn / 128, Nqkv / 128), 256, 0, stream>>>(
        x_bf, WtA, b_attn, Qb, Kb, Vb);
    vt_transpose_kernel<<<dim3(Bn * Hn, Tn / 64), 256, 0, stream>>>(Vb, Vtb);
    attn_mfma<<<dim3(Bn * Hn, 16), 256, 0, stream>>>(Qb, Kb, Vtb, Yb);
    transpose_cvt_kernel<<<dim3(Cn / 64, Cn / 64), 256, 0, stream>>>(
        W_proj, WtP, Cn, Cn);
    proj_gemm_mfma<<<dim3(Mn / 128, Cn / 128), 256, 0, stream>>>(
        Yb, WtP, b_proj, out);
}

// Round 9
// 266.554 us; speedup vs baseline: 1.7445x; 1.5821x over previous
//
#include <hip/hip_runtime.h>
#include <hip/hip_bf16.h>

typedef short s16x8 __attribute__((ext_vector_type(8)));
typedef float f32x4 __attribute__((ext_vector_type(4)));

#define MFMA_BF16(A, B, C) __builtin_amdgcn_mfma_f32_16x16x32_bf16(A, B, C, 0, 0, 0)

constexpr int Bn = 4, Tn = 2048, Cn = 1024, Hn = 16, Dn = 64;
constexpr int Mn = Bn * Tn;      // 8192
constexpr int Nqkv = 3 * Cn;     // 3072
constexpr float SC = 0.125f * 1.44269504089f;  // 1/sqrt(D) * log2(e)

__device__ __forceinline__ ushort f2bfu(float f) {
    __hip_bfloat16 h = __float2bfloat16(f);
    return *reinterpret_cast<ushort*>(&h);
}
__device__ __forceinline__ uint pkbf(float a, float b) {
    __hip_bfloat162 h = __float22bfloat162_rn(make_float2(a, b));
    return *reinterpret_cast<uint*>(&h);
}

// async global->LDS, 16B per lane; LDS dest = wave-uniform base + lane*16.
__device__ __forceinline__ void gl_lds16(const void* g, void* l) {
    __builtin_amdgcn_global_load_lds(
        (const __attribute__((address_space(1))) void*)(uintptr_t)g,
        (__attribute__((address_space(3))) void*)(uint32_t)(uintptr_t)l,
        16, 0, 0);
}

// ---------------------------------------------------------------------------
// fp32 -> bf16 elementwise (x)
// ---------------------------------------------------------------------------
__global__ __launch_bounds__(256) void conv_bf16_kernel(
    const float* __restrict__ src, ushort* __restrict__ dst, int n4)
{
    int i = blockIdx.x * blockDim.x + threadIdx.x;
    int stride = gridDim.x * blockDim.x;
    for (; i < n4; i += stride) {
        float4 v = ((const float4*)src)[i];
        ushort4 o;
        o.x = f2bfu(v.x); o.y = f2bfu(v.y); o.z = f2bfu(v.z); o.w = f2bfu(v.w);
        ((ushort4*)dst)[i] = o;
    }
}

// ---------------------------------------------------------------------------
// W [K][N] fp32  ->  Wt [N][K] bf16   (64x64 tiles via LDS)
// ---------------------------------------------------------------------------
__global__ __launch_bounds__(256) void transpose_cvt_kernel(
    const float* __restrict__ W, ushort* __restrict__ Wt, int K, int N)
{
    __shared__ __align__(16) float Ls[64][68];
    const int t = threadIdx.x;
    const int n0 = blockIdx.x * 64, k0 = blockIdx.y * 64;
#pragma unroll
    for (int p = 0; p < 4; ++p) {
        int r = (t >> 4) + p * 16;
        int c = (t & 15) * 4;
        *(float4*)&Ls[r][c] = *(const float4*)&W[(size_t)(k0 + r) * N + n0 + c];
    }
    __syncthreads();
    const int n = t >> 2;
    const int ks = (t & 3) * 16;
    union { ushort s[16]; uint4 u[2]; } tmp;
#pragma unroll
    for (int j = 0; j < 16; ++j) tmp.s[j] = f2bfu(Ls[ks + j][n]);
    uint4* dp = (uint4*)&Wt[(size_t)(n0 + n) * K + k0 + ks];
    dp[0] = tmp.u[0];
    dp[1] = tmp.u[1];
}

// ---------------------------------------------------------------------------
// V [bh][t][d] bf16 -> Vt [bh][d][t] bf16 (4x4 in-register transpose)
// ---------------------------------------------------------------------------
__global__ __launch_bounds__(256) void vt_transpose_kernel(
    const ushort* __restrict__ V, ushort* __restrict__ Vt)
{
    const int tid = threadIdx.x;
    const int bh = blockIdx.x;
    const int kt0 = blockIdx.y * 64;
    const ushort* src = V + (size_t)bh * Tn * Dn;
    ushort* dst = Vt + (size_t)bh * Dn * Tn;
    const int vk = (tid & 15) * 4, vd = (tid >> 4) * 4;
    const ushort* g = src + (size_t)(kt0 + vk) * Dn + vd;
    ushort4 v0 = *(const ushort4*)(g);
    ushort4 v1 = *(const ushort4*)(g + Dn);
    ushort4 v2 = *(const ushort4*)(g + 2 * Dn);
    ushort4 v3 = *(const ushort4*)(g + 3 * Dn);
    ushort4 t0, t1, t2, t3;
    t0.x = v0.x; t0.y = v1.x; t0.z = v2.x; t0.w = v3.x;
    t1.x = v0.y; t1.y = v1.y; t1.z = v2.y; t1.w = v3.y;
    t2.x = v0.z; t2.y = v1.z; t2.z = v2.z; t2.w = v3.z;
    t3.x = v0.w; t3.y = v1.w; t3.z = v2.w; t3.w = v3.w;
    *(ushort4*)(dst + (size_t)(vd + 0) * Tn + kt0 + vk) = t0;
    *(ushort4*)(dst + (size_t)(vd + 1) * Tn + kt0 + vk) = t1;
    *(ushort4*)(dst + (size_t)(vd + 2) * Tn + kt0 + vk) = t2;
    *(ushort4*)(dst + (size_t)(vd + 3) * Tn + kt0 + vk) = t3;
}

// ---------------------------------------------------------------------------
// QKV GEMM, m97-style staging. Q outputs pre-scaled by SC (exp2 domain).
// ---------------------------------------------------------------------------
__global__ __launch_bounds__(256) void qkv_gemm_mfma(
    const ushort* __restrict__ A, const ushort* __restrict__ Bt,
    const float* __restrict__ bias,
    ushort* __restrict__ Qo, ushort* __restrict__ Ko, ushort* __restrict__ Vo)
{
    __shared__ __align__(16) ushort As[128 * 64];
    __shared__ __align__(16) ushort Bs[128 * 64];
    const int tid = threadIdx.x;
    const int m0 = blockIdx.x * 128, n0 = blockIdx.y * 128;
    const int w = tid >> 6, lane = tid & 63, l15 = lane & 15, qd = lane >> 4;
    const int wm = (w >> 1) * 64, wn = (w & 1) * 64;
    const int lrow = lane >> 3;
    const int lchunk = (lane & 7) ^ (lrow & 7);

    const ushort* gA = A + (size_t)(m0 + w * 32 + lrow) * Cn + lchunk * 8;
    const ushort* gB = Bt + (size_t)(n0 + w * 32 + lrow) * Cn + lchunk * 8;
    ushort* lA = &As[(w * 32) * 64];
    ushort* lB = &Bs[(w * 32) * 64];

    f32x4 acc[4][4] = {};

    for (int k0 = 0; k0 < Cn; k0 += 64) {
        __syncthreads();
#pragma unroll
        for (int t = 0; t < 4; ++t) {
            gl_lds16(gA + (size_t)t * 8 * Cn + k0, lA + t * 8 * 64);
            gl_lds16(gB + (size_t)t * 8 * Cn + k0, lB + t * 8 * 64);
        }
        __syncthreads();
#pragma unroll
        for (int ks = 0; ks < 2; ++ks) {
            const int xs = (((ks * 4 + qd) ^ (l15 & 7))) * 8;
            s16x8 af[4], bfr[4];
#pragma unroll
            for (int i = 0; i < 4; ++i) {
                af[i]  = *(const s16x8*)&As[(wm + i * 16 + l15) * 64 + xs];
                bfr[i] = *(const s16x8*)&Bs[(wn + i * 16 + l15) * 64 + xs];
            }
#pragma unroll
            for (int mt = 0; mt < 4; ++mt)
#pragma unroll
                for (int nt = 0; nt < 4; ++nt)
                    acc[mt][nt] = MFMA_BF16(af[mt], bfr[nt], acc[mt][nt]);
        }
    }

#pragma unroll
    for (int nt = 0; nt < 4; ++nt) {
        int n_g = n0 + wn + nt * 16 + l15;
        float bv = bias[n_g];
        int sel = n_g >> 10;
        int h = (n_g >> 6) & 15;
        int d = n_g & 63;
        ushort* O = (sel == 0) ? Qo : ((sel == 1) ? Ko : Vo);
        float scl = (sel == 0) ? SC : 1.0f;
#pragma unroll
        for (int mt = 0; mt < 4; ++mt) {
#pragma unroll
            for (int r = 0; r < 4; ++r) {
                int m_g = m0 + wm + mt * 16 + qd * 4 + r;
                int b = m_g >> 11, t = m_g & 2047;
                O[(((size_t)(b * Hn + h) * Tn + t) << 6) + d] =
                    f2bfu((acc[mt][nt][r] + bv) * scl);
            }
        }
    }
}

// ---------------------------------------------------------------------------
// MFMA flash attention, async-DMA pipelined:
//  - K and Vt tiles staged cooperatively via global_load_lds(16B), double-
//    buffered; tile kt+1's DMA issued right after the barrier publishing kt
//    -> loads overlap a full tile of compute; ONE barrier per kt.
//  - swizzle realized by permuting SOURCE addresses (DMA dest is lane-linear)
//  - transposed-S formulation, exp2 softmax, wave-private P^T LDS round trip
//  - grid (bh=64, pair=16): XCD-local K/Vt reuse; 1024 blocks = 4/CU (40KB)
// ---------------------------------------------------------------------------
__global__ __launch_bounds__(256, 4) void attn_mfma(
    const ushort* __restrict__ Q, const ushort* __restrict__ K,
    const ushort* __restrict__ Vt, ushort* __restrict__ Y)
{
    __shared__ __align__(16) ushort Ks[2][64 * 64];
    __shared__ __align__(16) ushort Vs[2][64 * 64];
    __shared__ __align__(16) ushort Ps[64 * 64];

    const int tid = threadIdx.x;
    const int bh = blockIdx.x, bx = blockIdx.y;
    const int w = tid >> 6, lane = tid & 63, l15 = lane & 15, qd = lane >> 4;
    const size_t base = (size_t)bh * Tn * Dn;
    const int lrow = lane >> 3;                   // 0..7
    const int lchunk = (lane & 7) ^ (lrow & 7);   // source-side swizzle
    const int q_l = w * 16 + l15;
    const int frow = (w * 16 + l15) * 64;
    const int fx0 = ((0 * 4 + qd) ^ (l15 & 7)) * 8;
    const int fx1 = ((1 * 4 + qd) ^ (l15 & 7)) * 8;
    const int b = bh >> 4, h = bh & 15;

    // staging sources: wave w stages rows w*16 .. w*16+15 of each tile
    const ushort* Kg = K + base + (size_t)(w * 16 + lrow) * Dn + lchunk * 8;
    const ushort* Vg = Vt + base + (size_t)(w * 16 + lrow) * Tn + lchunk * 8;
    // Q fragments direct from global
    const ushort* Qp = Q + base + (size_t)l15 * Dn + qd * 8;

#pragma unroll
    for (int half = 0; half < 2; ++half) {
        const int qt = half ? (31 - bx) : bx;

        const ushort* qrow = Qp + (size_t)(qt * 64 + w * 16) * Dn;
        s16x8 qf0 = *(const s16x8*)(qrow);
        s16x8 qf1 = *(const s16x8*)(qrow + 32);

        __syncthreads();   // previous half's LDS reads complete
        // issue DMA for tile 0 -> buffer 0
#pragma unroll
        for (int t = 0; t < 2; ++t) {
            gl_lds16(Kg + (size_t)(t * 8) * Dn, &Ks[0][(w * 16 + t * 8) * 64]);
            gl_lds16(Vg + (size_t)(t * 8) * Tn, &Vs[0][(w * 16 + t * 8) * 64]);
        }

        float m_run = -1e30f, l_run = 0.f;
        f32x4 o[4] = {};   // O^T[d=dt*16+qd*4+r][q=l15]

        for (int kt = 0; kt <= qt; ++kt) {
            const int buf = kt & 1;
            __syncthreads();   // drains own vmcnt -> tile kt ready; buf^1 free
            if (kt < qt) {     // issue DMA for kt+1 -> buf^1 (overlaps compute)
#pragma unroll
                for (int t = 0; t < 2; ++t) {
                    gl_lds16(Kg + (size_t)((kt + 1) * 64 + t * 8) * Dn,
                             &Ks[buf ^ 1][(w * 16 + t * 8) * 64]);
                    gl_lds16(Vg + (size_t)(t * 8) * Tn + (kt + 1) * 64,
                             &Vs[buf ^ 1][(w * 16 + t * 8) * 64]);
                }
            }

            // S^T = K·Q^T (exp2 domain via pre-scaled Q)
            f32x4 s[4] = {};
#pragma unroll
            for (int nt = 0; nt < 4; ++nt) {
                s16x8 kf = *(const s16x8*)&Ks[buf][(nt * 16 + l15) * 64 + fx0];
                s[nt] = MFMA_BF16(kf, qf0, s[nt]);
            }
#pragma unroll
            for (int nt = 0; nt < 4; ++nt) {
                s16x8 kf = *(const s16x8*)&Ks[buf][(nt * 16 + l15) * 64 + fx1];
                s[nt] = MFMA_BF16(kf, qf1, s[nt]);
            }

            if (kt == qt) {
#pragma unroll
                for (int nt = 0; nt < 4; ++nt)
#pragma unroll
                    for (int r = 0; r < 4; ++r)
                        if (nt * 16 + qd * 4 + r > q_l) s[nt][r] = -1e30f;
            }

            // online softmax over keys: 15 in-lane fmax + 2 shuffles
            float mx = s[0][0];
#pragma unroll
            for (int nt = 0; nt < 4; ++nt)
#pragma unroll
                for (int r = 0; r < 4; ++r) mx = fmaxf(mx, s[nt][r]);
            mx = fmaxf(mx, __shfl_xor(mx, 16));
            mx = fmaxf(mx, __shfl_xor(mx, 32));

            if (__any(mx > m_run)) {
                float m_new = fmaxf(m_run, mx);
                float alpha = exp2f(m_run - m_new);
                m_run = m_new;
                l_run *= alpha;
#pragma unroll
                for (int dt = 0; dt < 4; ++dt)
#pragma unroll
                    for (int r = 0; r < 4; ++r) o[dt][r] *= alpha;
            }
            float ls = 0.f;
#pragma unroll
            for (int nt = 0; nt < 4; ++nt)
#pragma unroll
                for (int r = 0; r < 4; ++r) {
                    float p = exp2f(s[nt][r] - m_run);
                    s[nt][r] = p;
                    ls += p;
                }
            ls += __shfl_xor(ls, 16);
            ls += __shfl_xor(ls, 32);
            l_run += ls;

            // P^T -> wave-private LDS rows (packed bf16 pairs)
#pragma unroll
            for (int nt = 0; nt < 4; ++nt) {
                uint2 pk;
                pk.x = pkbf(s[nt][0], s[nt][1]);
                pk.y = pkbf(s[nt][2], s[nt][3]);
                const int pc = 2 * nt + (qd >> 1), po = (qd & 1) * 4;
                *(uint2*)&Ps[frow + ((pc ^ (l15 & 7)) * 8) + po] = pk;
            }

            // O^T += V^T · P^T  (same-wave LDS round trip; no barrier)
            {
                s16x8 pb = *(const s16x8*)&Ps[frow + fx0];
#pragma unroll
                for (int dt = 0; dt < 4; ++dt) {
                    s16x8 vf = *(const s16x8*)&Vs[buf][(dt * 16 + l15) * 64 + fx0];
                    o[dt] = MFMA_BF16(vf, pb, o[dt]);
                }
                pb = *(const s16x8*)&Ps[frow + fx1];
#pragma unroll
                for (int dt = 0; dt < 4; ++dt) {
                    s16x8 vf = *(const s16x8*)&Vs[buf][(dt * 16 + l15) * 64 + fx1];
                    o[dt] = MFMA_BF16(vf, pb, o[dt]);
                }
            }
        }

        // epilogue: O^T[d][q=l15] -> Y[b, t=q_global, h*64+d]
        const float inv = 1.f / l_run;
        const int t_g = qt * 64 + w * 16 + l15;
        ushort* yp = Y + ((size_t)(b * Tn + t_g)) * Cn + h * Dn + qd * 4;
#pragma unroll
        for (int dt = 0; dt < 4; ++dt) {
            uint2 pk;
            pk.x = pkbf(o[dt][0] * inv, o[dt][1] * inv);
            pk.y = pkbf(o[dt][2] * inv, o[dt][3] * inv);
            *(uint2*)(yp + dt * 16) = pk;
        }
    }
}

// ---------------------------------------------------------------------------
// Proj GEMM: Y [8192][1024] bf16, Wt [1024][1024] bf16 -> out fp32
// ---------------------------------------------------------------------------
__global__ __launch_bounds__(256) void proj_gemm_mfma(
    const ushort* __restrict__ A, const ushort* __restrict__ Bt,
    const float* __restrict__ bias, float* __restrict__ out)
{
    __shared__ __align__(16) ushort As[128 * 64];
    __shared__ __align__(16) ushort Bs[128 * 64];
    const int tid = threadIdx.x;
    const int m0 = blockIdx.x * 128, n0 = blockIdx.y * 128;
    const int w = tid >> 6, lane = tid & 63, l15 = lane & 15, qd = lane >> 4;
    const int wm = (w >> 1) * 64, wn = (w & 1) * 64;
    const int lrow = lane >> 3;
    const int lchunk = (lane & 7) ^ (lrow & 7);

    const ushort* gA = A + (size_t)(m0 + w * 32 + lrow) * Cn + lchunk * 8;
    const ushort* gB = Bt + (size_t)(n0 + w * 32 + lrow) * Cn + lchunk * 8;
    ushort* lA = &As[(w * 32) * 64];
    ushort* lB = &Bs[(w * 32) * 64];

    f32x4 acc[4][4] = {};

    for (int k0 = 0; k0 < Cn; k0 += 64) {
        __syncthreads();
#pragma unroll
        for (int t = 0; t < 4; ++t) {
            gl_lds16(gA + (size_t)t * 8 * Cn + k0, lA + t * 8 * 64);
            gl_lds16(gB + (size_t)t * 8 * Cn + k0, lB + t * 8 * 64);
        }
        __syncthreads();
#pragma unroll
        for (int ks = 0; ks < 2; ++ks) {
            const int xs = (((ks * 4 + qd) ^ (l15 & 7))) * 8;
            s16x8 af[4], bfr[4];
#pragma unroll
            for (int i = 0; i < 4; ++i) {
                af[i]  = *(const s16x8*)&As[(wm + i * 16 + l15) * 64 + xs];
                bfr[i] = *(const s16x8*)&Bs[(wn + i * 16 + l15) * 64 + xs];
            }
#pragma unroll
            for (int mt = 0; mt < 4; ++mt)
#pragma unroll
                for (int nt = 0; nt < 4; ++nt)
                    acc[mt][nt] = MFMA_BF16(af[mt], bfr[nt], acc[mt][nt]);
        }
    }

#pragma unroll
    for (int nt = 0; nt < 4; ++nt) {
        int n_g = n0 + wn + nt * 16 + l15;
        float bv = bias[n_g];
#pragma unroll
        for (int mt = 0; mt < 4; ++mt) {
#pragma unroll
            for (int r = 0; r < 4; ++r) {
                int m_g = m0 + wm + mt * 16 + qd * 4 + r;
                out[(size_t)m_g * Cn + n_g] = acc[mt][nt][r] + bv;
            }
        }
    }
}

// ---------------------------------------------------------------------------
extern "C" void kernel_launch(void* const* d_in, const int* in_sizes, int n_in,
                              void* d_out, int out_size, void* d_ws, size_t ws_size,
                              hipStream_t stream) {
    const float* x      = (const float*)d_in[0];
    const float* W_attn = (const float*)d_in[1];
    const float* b_attn = (const float*)d_in[2];
    const float* W_proj = (const float*)d_in[3];
    const float* b_proj = (const float*)d_in[4];
    float* out = (float*)d_out;

    // ws: Q, K, V [B,H,T,D] bf16, Y [B,T,C] bf16
    constexpr size_t PER = (size_t)Mn * Cn;  // 8388608 elems
    ushort* Qb = (ushort*)d_ws;
    ushort* Kb = Qb + PER;
    ushort* Vb = Kb + PER;
    ushort* Yb = Vb + PER;

    // d_out as scratch (33.5 MB):
    //   phase 1 (pre-GEMM): WtA [3072][1024] bf16 (6.3MB) + x_bf (16.8MB)
    //   phase 2 (post-GEMM, pre-proj): Vtb [bh][d][t] bf16 (16.8MB) at offset 0
    ushort* WtA  = (ushort*)d_out;
    ushort* x_bf = WtA + (size_t)Nqkv * Cn;
    ushort* Vtb  = (ushort*)d_out;     // overwrites WtA/x_bf after qkv_gemm
    ushort* WtP  = Qb;                 // reuses Q buffer (dead after attention)

    conv_bf16_kernel<<<1024, 256, 0, stream>>>(x, x_bf, (int)(PER / 4));
    transpose_cvt_kernel<<<dim3(Nqkv / 64, Cn / 64), 256, 0, stream>>>(
        W_attn, WtA, Cn, Nqkv);
    qkv_gemm_mfma<<<dim3(Mn / 128, Nqkv / 128), 256, 0, stream>>>(
        x_bf, WtA, b_attn, Qb, Kb, Vb);
    vt_transpose_kernel<<<dim3(Bn * Hn, Tn / 64), 256, 0, stream>>>(Vb, Vtb);
    attn_mfma<<<dim3(Bn * Hn, 16), 256, 0, stream>>>(Qb, Kb, Vtb, Yb);
    transpose_cvt_kernel<<<dim3(Cn / 64, Cn / 64), 256, 0, stream>>>(
        W_proj, WtP, Cn, Cn);
    proj_gemm_mfma<<<dim3(Mn / 128, Cn / 128), 256, 0, stream>>>(
        Yb, WtP, b_proj, out);
}